// Round 1
// baseline (1425.052 us; speedup 1.0000x reference)
//
#include <hip/hip_runtime.h>
#include <hip/hip_bf16.h>

#define DFEAT 128
#define THETA 0.25f

// ---------------------------------------------------------------------------
// Kernel 1: SpMM scatter.  One wave (64 lanes) per edge; lane i handles
// features [2i, 2i+1].  hi accumulates in d_out (same shape as output).
// ---------------------------------------------------------------------------
__global__ __launch_bounds__(256) void gcn_scatter(
    const float* __restrict__ input,
    const int*   __restrict__ esrc,
    const int*   __restrict__ edst,
    const float* __restrict__ eval_,
    float*       __restrict__ hi,
    int E)
{
    long long t = (long long)blockIdx.x * blockDim.x + threadIdx.x;
    int e = (int)(t >> 6);
    if (e >= E) return;
    int lane = (int)(t & 63);

    int   s = esrc[e];
    int   d = edst[e];
    float v = eval_[e];

    const float2 x = *reinterpret_cast<const float2*>(
        &input[(size_t)s * DFEAT + lane * 2]);
    float* p = &hi[(size_t)d * DFEAT + lane * 2];
    unsafeAtomicAdd(p,     x.x * v);   // hardware global_atomic_add_f32
    unsafeAtomicAdd(p + 1, x.y * v);
}

// ---------------------------------------------------------------------------
// Kernel 2: epilogue.  out (holding hi) -> support = (1-a)*hi + a*h0,
// out = support @ W' + input,  W' = THETA*W + (1-THETA)*I  (bf16 in LDS).
// In-place safe: each block stages its rows to LDS before overwriting them.
// ---------------------------------------------------------------------------
__global__ __launch_bounds__(256) void gcn_epilogue(
    float*       __restrict__ out,     // holds hi on entry
    const float* __restrict__ h0,
    const float* __restrict__ inp,
    const float* __restrict__ W,
    const float* __restrict__ alpha,
    int N)
{
    __shared__ __hip_bfloat16 Wl[DFEAT * DFEAT];   // 32 KB
    __shared__ float4 S4[16][DFEAT / 4];           // 8 KB (16 staged rows)

    const float a   = 0.5f / (1.0f + __expf(-alpha[0]));
    const float oma = 1.0f - a;

    // Build W' = THETA*W + (1-THETA)*I into LDS (bf16)
    for (int i = threadIdx.x; i < DFEAT * DFEAT; i += 256) {
        int k = i >> 7, j = i & 127;
        float w = W[i] * THETA;
        if (k == j) w += 1.0f - THETA;
        Wl[i] = __float2bfloat16(w);
    }

    const int j  = threadIdx.x & 127;   // output column
    const int rg = threadIdx.x >> 7;    // row group: 0 -> rows 0..7, 1 -> 8..15

    for (int base = blockIdx.x * 16; base < N; base += gridDim.x * 16) {
        const int rows = min(16, N - base);

        __syncthreads();  // S4 free (prev iter consumed) & Wl ready (1st iter)

        // Stage support rows: S = (1-a)*hi + a*h0   (vectorized float4)
        for (int i = threadIdx.x; i < rows * 32; i += 256) {
            int r = i >> 5, c = i & 31;
            size_t g = (size_t)(base + r) * (DFEAT / 4) + c;
            float4 hv  = reinterpret_cast<const float4*>(out)[g];
            float4 h0v = reinterpret_cast<const float4*>(h0)[g];
            float4 sv;
            sv.x = oma * hv.x + a * h0v.x;
            sv.y = oma * hv.y + a * h0v.y;
            sv.z = oma * hv.z + a * h0v.z;
            sv.w = oma * hv.w + a * h0v.w;
            S4[r][c] = sv;
        }
        __syncthreads();

        // Register-tiled GEMM: thread owns column j, 8 rows
        float acc[8];
        #pragma unroll
        for (int r = 0; r < 8; r++) acc[r] = 0.0f;

        for (int k = 0; k < DFEAT; k += 4) {
            float w0 = __bfloat162float(Wl[(k + 0) * DFEAT + j]);
            float w1 = __bfloat162float(Wl[(k + 1) * DFEAT + j]);
            float w2 = __bfloat162float(Wl[(k + 2) * DFEAT + j]);
            float w3 = __bfloat162float(Wl[(k + 3) * DFEAT + j]);
            #pragma unroll
            for (int r = 0; r < 8; r++) {
                float4 s4 = S4[rg * 8 + r][k >> 2];   // wave-uniform broadcast
                acc[r] = fmaf(s4.x, w0, acc[r]);
                acc[r] = fmaf(s4.y, w1, acc[r]);
                acc[r] = fmaf(s4.z, w2, acc[r]);
                acc[r] = fmaf(s4.w, w3, acc[r]);
            }
        }

        // Write: out = acc + input  (rows already fully consumed into S4)
        #pragma unroll
        for (int r = 0; r < 8; r++) {
            int rr = rg * 8 + r;
            if (rr < rows) {
                size_t g = (size_t)(base + rr) * DFEAT + j;
                out[g] = acc[r] + inp[g];
            }
        }
    }
}

extern "C" void kernel_launch(void* const* d_in, const int* in_sizes, int n_in,
                              void* d_out, int out_size, void* d_ws, size_t ws_size,
                              hipStream_t stream) {
    const float* input = (const float*)d_in[0];
    const int*   esrc  = (const int*)  d_in[1];
    const int*   edst  = (const int*)  d_in[2];
    const float* eval_ = (const float*)d_in[3];
    const float* h0    = (const float*)d_in[4];
    const float* W     = (const float*)d_in[5];
    const float* alpha = (const float*)d_in[6];

    const int N = in_sizes[0] / DFEAT;
    const int E = in_sizes[1];
    float* out = (float*)d_out;

    // hi accumulates in d_out; zero it first (harness poisons with 0xAA).
    hipMemsetAsync(out, 0, (size_t)N * DFEAT * sizeof(float), stream);

    long long threads = (long long)E * 64;
    unsigned  nblk    = (unsigned)((threads + 255) / 256);
    gcn_scatter<<<dim3(nblk), dim3(256), 0, stream>>>(input, esrc, edst, eval_, out, E);

    gcn_epilogue<<<dim3(2048), dim3(256), 0, stream>>>(out, h0, input, W, alpha, N);
}

// Round 2
// 426.269 us; speedup vs baseline: 3.3431x; 3.3431x over previous
//
#include <hip/hip_runtime.h>
#include <hip/hip_bf16.h>

#define DFEAT 128
#define THETA 0.25f

// ===========================================================================
// CSR build: histogram -> 3-kernel exclusive scan -> slot scatter
// ===========================================================================
__global__ void k_hist(const int* __restrict__ edst, int* __restrict__ cnt, int E) {
    int e = blockIdx.x * blockDim.x + threadIdx.x;
    if (e < E) atomicAdd(&cnt[edst[e]], 1);
}

__global__ void k_scanA(const int* __restrict__ cnt, int* __restrict__ part, int N) {
    __shared__ int s[256];
    int i = blockIdx.x * 256 + threadIdx.x;
    s[threadIdx.x] = (i < N) ? cnt[i] : 0;
    __syncthreads();
    for (int off = 128; off > 0; off >>= 1) {
        if (threadIdx.x < off) s[threadIdx.x] += s[threadIdx.x + off];
        __syncthreads();
    }
    if (threadIdx.x == 0) part[blockIdx.x] = s[0];
}

// Exclusive scan of B block-sums (B <= 1024), also writes rowptr[N] = total.
__global__ void k_scanB(int* __restrict__ part, int* __restrict__ rowptr, int B, int N) {
    __shared__ int buf[1024];
    int t = threadIdx.x;
    buf[t] = (t < B) ? part[t] : 0;
    __syncthreads();
    for (int off = 1; off < 1024; off <<= 1) {
        int y = (t >= off) ? buf[t - off] : 0;
        __syncthreads();
        buf[t] += y;
        __syncthreads();
    }
    if (t < B) part[t] = (t == 0) ? 0 : buf[t - 1];
    if (t == B - 1) rowptr[N] = buf[t];
}

__global__ void k_scanC(const int* __restrict__ cnt, const int* __restrict__ part,
                        int* __restrict__ rowptr, int N) {
    __shared__ int buf[256];
    int t = threadIdx.x;
    int i = blockIdx.x * 256 + t;
    buf[t] = (i < N) ? cnt[i] : 0;
    __syncthreads();
    for (int off = 1; off < 256; off <<= 1) {
        int y = (t >= off) ? buf[t - off] : 0;
        __syncthreads();
        buf[t] += y;
        __syncthreads();
    }
    if (i < N) rowptr[i] = part[blockIdx.x] + ((t == 0) ? 0 : buf[t - 1]);
}

__global__ void k_slot(const int* __restrict__ esrc, const int* __restrict__ edst,
                       const float* __restrict__ eval_, const int* __restrict__ rowptr,
                       int* __restrict__ cnt, int2* __restrict__ csr, int E) {
    int e = blockIdx.x * blockDim.x + threadIdx.x;
    if (e >= E) return;
    int d = edst[e];
    int r = atomicSub(&cnt[d], 1);            // old value; slots r-1 .. 0
    csr[rowptr[d] + r - 1] = make_int2(esrc[e], __float_as_int(eval_[e]));
}

// ===========================================================================
// Gather: one wave per node, lane owns feats [2*lane, 2*lane+1].
// Writes support = (1-a)*hi + a*h0 directly.
// ===========================================================================
__global__ __launch_bounds__(256) void k_gather(
    const float* __restrict__ input, const int2* __restrict__ csr,
    const int* __restrict__ rowptr, const float* __restrict__ h0,
    const float* __restrict__ alpha, float* __restrict__ out, int N)
{
    int w    = (int)(((long long)blockIdx.x * blockDim.x + threadIdx.x) >> 6);
    int lane = threadIdx.x & 63;
    if (w >= N) return;

    int beg = rowptr[w], end = rowptr[w + 1];
    float ax = 0.f, ay = 0.f, bx = 0.f, by = 0.f;
    int i = beg;
    for (; i + 2 <= end; i += 2) {           // 2-way ILP unroll
        int2 p0 = csr[i], p1 = csr[i + 1];
        float2 x0 = *(const float2*)&input[(size_t)p0.x * DFEAT + lane * 2];
        float2 x1 = *(const float2*)&input[(size_t)p1.x * DFEAT + lane * 2];
        float v0 = __int_as_float(p0.y), v1 = __int_as_float(p1.y);
        ax = fmaf(v0, x0.x, ax); ay = fmaf(v0, x0.y, ay);
        bx = fmaf(v1, x1.x, bx); by = fmaf(v1, x1.y, by);
    }
    if (i < end) {
        int2 p = csr[i];
        float2 x = *(const float2*)&input[(size_t)p.x * DFEAT + lane * 2];
        float v = __int_as_float(p.y);
        ax = fmaf(v, x.x, ax); ay = fmaf(v, x.y, ay);
    }
    float hx = ax + bx, hy = ay + by;

    float a   = 0.5f / (1.0f + __expf(-alpha[0]));
    float oma = 1.0f - a;
    float2 h0v = *(const float2*)&h0[(size_t)w * DFEAT + lane * 2];
    float2 sv;
    sv.x = oma * hx + a * h0v.x;
    sv.y = oma * hy + a * h0v.y;
    *(float2*)&out[(size_t)w * DFEAT + lane * 2] = sv;
}

// ===========================================================================
// Fallback scatter (atomic) — used only if ws_size is too small.
// ===========================================================================
__global__ __launch_bounds__(256) void gcn_scatter(
    const float* __restrict__ input, const int* __restrict__ esrc,
    const int* __restrict__ edst, const float* __restrict__ eval_,
    float* __restrict__ hi, int E)
{
    long long t = (long long)blockIdx.x * blockDim.x + threadIdx.x;
    int e = (int)(t >> 6);
    if (e >= E) return;
    int lane = (int)(t & 63);
    int s = esrc[e]; int d = edst[e]; float v = eval_[e];
    const float2 x = *reinterpret_cast<const float2*>(&input[(size_t)s * DFEAT + lane * 2]);
    float* p = &hi[(size_t)d * DFEAT + lane * 2];
    unsafeAtomicAdd(p,     x.x * v);
    unsafeAtomicAdd(p + 1, x.y * v);
}

// ===========================================================================
// Epilogue: out = S @ W' + input, W' = THETA*W + (1-THETA)*I (bf16 LDS).
// BLEND=true: out holds hi, blend with h0 first (fallback path).
// BLEND=false: out already holds support.
// ===========================================================================
template <bool BLEND>
__global__ __launch_bounds__(256) void gcn_epilogue(
    float* __restrict__ out, const float* __restrict__ h0,
    const float* __restrict__ inp, const float* __restrict__ W,
    const float* __restrict__ alpha, int N)
{
    __shared__ __hip_bfloat16 Wl[DFEAT * DFEAT];   // 32 KB
    __shared__ float4 S4[16][DFEAT / 4];           // 8 KB

    const float a   = 0.5f / (1.0f + __expf(-alpha[0]));
    const float oma = 1.0f - a;

    for (int i = threadIdx.x; i < DFEAT * DFEAT; i += 256) {
        int k = i >> 7, j = i & 127;
        float w = W[i] * THETA;
        if (k == j) w += 1.0f - THETA;
        Wl[i] = __float2bfloat16(w);
    }

    const int j  = threadIdx.x & 127;
    const int rg = threadIdx.x >> 7;

    for (int base = blockIdx.x * 16; base < N; base += gridDim.x * 16) {
        const int rows = min(16, N - base);
        __syncthreads();
        for (int i = threadIdx.x; i < rows * 32; i += 256) {
            int r = i >> 5, c = i & 31;
            size_t g = (size_t)(base + r) * (DFEAT / 4) + c;
            float4 hv = reinterpret_cast<const float4*>(out)[g];
            float4 sv;
            if (BLEND) {
                float4 h0v = reinterpret_cast<const float4*>(h0)[g];
                sv.x = oma * hv.x + a * h0v.x;
                sv.y = oma * hv.y + a * h0v.y;
                sv.z = oma * hv.z + a * h0v.z;
                sv.w = oma * hv.w + a * h0v.w;
            } else {
                sv = hv;
            }
            S4[r][c] = sv;
        }
        __syncthreads();

        float acc[8];
        #pragma unroll
        for (int r = 0; r < 8; r++) acc[r] = 0.0f;
        for (int k = 0; k < DFEAT; k += 4) {
            float w0 = __bfloat162float(Wl[(k + 0) * DFEAT + j]);
            float w1 = __bfloat162float(Wl[(k + 1) * DFEAT + j]);
            float w2 = __bfloat162float(Wl[(k + 2) * DFEAT + j]);
            float w3 = __bfloat162float(Wl[(k + 3) * DFEAT + j]);
            #pragma unroll
            for (int r = 0; r < 8; r++) {
                float4 s4 = S4[rg * 8 + r][k >> 2];
                acc[r] = fmaf(s4.x, w0, acc[r]);
                acc[r] = fmaf(s4.y, w1, acc[r]);
                acc[r] = fmaf(s4.z, w2, acc[r]);
                acc[r] = fmaf(s4.w, w3, acc[r]);
            }
        }
        #pragma unroll
        for (int r = 0; r < 8; r++) {
            int rr = rg * 8 + r;
            if (rr < rows) {
                size_t g = (size_t)(base + rr) * DFEAT + j;
                out[g] = acc[r] + inp[g];
            }
        }
    }
}

extern "C" void kernel_launch(void* const* d_in, const int* in_sizes, int n_in,
                              void* d_out, int out_size, void* d_ws, size_t ws_size,
                              hipStream_t stream) {
    const float* input = (const float*)d_in[0];
    const int*   esrc  = (const int*)  d_in[1];
    const int*   edst  = (const int*)  d_in[2];
    const float* eval_ = (const float*)d_in[3];
    const float* h0    = (const float*)d_in[4];
    const float* W     = (const float*)d_in[5];
    const float* alpha = (const float*)d_in[6];

    const int N = in_sizes[0] / DFEAT;
    const int E = in_sizes[1];
    float* out = (float*)d_out;

    // ws layout (ints): rowptr[N+1] | cnt[N] | part[1024] | (8B-align) csr[E]
    size_t o_rowptr = 0;
    size_t o_cnt    = o_rowptr + (size_t)(N + 1);
    size_t o_part   = o_cnt + (size_t)N;
    size_t o_csr    = (o_part + 1024 + 1) & ~(size_t)1;   // int2-aligned
    size_t needed   = o_csr * 4 + (size_t)E * 8;

    const int B = (N + 255) / 256;   // scan blocks; must be <= 1024

    if (ws_size >= needed && B <= 1024) {
        int*  rowptr = (int*)d_ws + o_rowptr;
        int*  cnt    = (int*)d_ws + o_cnt;
        int*  part   = (int*)d_ws + o_part;
        int2* csr    = (int2*)((int*)d_ws + o_csr);

        hipMemsetAsync(cnt, 0, (size_t)N * sizeof(int), stream);
        k_hist <<<dim3((E + 255) / 256), dim3(256), 0, stream>>>(edst, cnt, E);
        k_scanA<<<dim3(B),              dim3(256), 0, stream>>>(cnt, part, N);
        k_scanB<<<dim3(1),              dim3(1024), 0, stream>>>(part, rowptr, B, N);
        k_scanC<<<dim3(B),              dim3(256), 0, stream>>>(cnt, part, rowptr, N);
        k_slot <<<dim3((E + 255) / 256), dim3(256), 0, stream>>>(esrc, edst, eval_,
                                                                 rowptr, cnt, csr, E);
        k_gather<<<dim3((N + 3) / 4),   dim3(256), 0, stream>>>(input, csr, rowptr,
                                                                h0, alpha, out, N);
        gcn_epilogue<false><<<dim3(2048), dim3(256), 0, stream>>>(out, h0, input, W,
                                                                  alpha, N);
    } else {
        // Fallback: atomic scatter path (R1)
        hipMemsetAsync(out, 0, (size_t)N * DFEAT * sizeof(float), stream);
        long long threads = (long long)E * 64;
        unsigned  nblk    = (unsigned)((threads + 255) / 256);
        gcn_scatter<<<dim3(nblk), dim3(256), 0, stream>>>(input, esrc, edst, eval_, out, E);
        gcn_epilogue<true><<<dim3(2048), dim3(256), 0, stream>>>(out, h0, input, W,
                                                                 alpha, N);
    }
}

// Round 3
// 371.066 us; speedup vs baseline: 3.8404x; 1.1488x over previous
//
#include <hip/hip_runtime.h>
#include <hip/hip_bf16.h>

#define DFEAT 128
#define THETA 0.25f

// ===========================================================================
// Convert input rows to bf16 (one thread per 8 floats)
// ===========================================================================
__device__ inline unsigned pk_bf16(float x, float y) {
    __hip_bfloat16 a = __float2bfloat16(x), b = __float2bfloat16(y);
    unsigned short ua = *reinterpret_cast<unsigned short*>(&a);
    unsigned short ub = *reinterpret_cast<unsigned short*>(&b);
    return (unsigned)ua | ((unsigned)ub << 16);
}

__global__ __launch_bounds__(256) void k_cvt(const float* __restrict__ in,
                                             uint4* __restrict__ o, int n8) {
    int i = blockIdx.x * blockDim.x + threadIdx.x;
    if (i >= n8) return;
    float4 a = reinterpret_cast<const float4*>(in)[(size_t)i * 2];
    float4 b = reinterpret_cast<const float4*>(in)[(size_t)i * 2 + 1];
    uint4 r;
    r.x = pk_bf16(a.x, a.y);
    r.y = pk_bf16(a.z, a.w);
    r.z = pk_bf16(b.x, b.y);
    r.w = pk_bf16(b.z, b.w);
    o[i] = r;
}

// ===========================================================================
// CSR build: histogram -> 3-kernel exclusive scan -> slot scatter
// ===========================================================================
__global__ void k_hist(const int* __restrict__ edst, int* __restrict__ cnt, int E) {
    int e = blockIdx.x * blockDim.x + threadIdx.x;
    if (e < E) atomicAdd(&cnt[edst[e]], 1);
}

__global__ void k_scanA(const int* __restrict__ cnt, int* __restrict__ part, int N) {
    __shared__ int s[256];
    int i = blockIdx.x * 256 + threadIdx.x;
    s[threadIdx.x] = (i < N) ? cnt[i] : 0;
    __syncthreads();
    for (int off = 128; off > 0; off >>= 1) {
        if (threadIdx.x < off) s[threadIdx.x] += s[threadIdx.x + off];
        __syncthreads();
    }
    if (threadIdx.x == 0) part[blockIdx.x] = s[0];
}

__global__ void k_scanB(int* __restrict__ part, int* __restrict__ rowptr, int B, int N) {
    __shared__ int buf[1024];
    int t = threadIdx.x;
    buf[t] = (t < B) ? part[t] : 0;
    __syncthreads();
    for (int off = 1; off < 1024; off <<= 1) {
        int y = (t >= off) ? buf[t - off] : 0;
        __syncthreads();
        buf[t] += y;
        __syncthreads();
    }
    if (t < B) part[t] = (t == 0) ? 0 : buf[t - 1];
    if (t == B - 1) rowptr[N] = buf[t];
}

__global__ void k_scanC(const int* __restrict__ cnt, const int* __restrict__ part,
                        int* __restrict__ rowptr, int N) {
    __shared__ int buf[256];
    int t = threadIdx.x;
    int i = blockIdx.x * 256 + t;
    buf[t] = (i < N) ? cnt[i] : 0;
    __syncthreads();
    for (int off = 1; off < 256; off <<= 1) {
        int y = (t >= off) ? buf[t - off] : 0;
        __syncthreads();
        buf[t] += y;
        __syncthreads();
    }
    if (i < N) rowptr[i] = part[blockIdx.x] + ((t == 0) ? 0 : buf[t - 1]);
}

__global__ void k_slot(const int* __restrict__ esrc, const int* __restrict__ edst,
                       const float* __restrict__ eval_, const int* __restrict__ rowptr,
                       int* __restrict__ cnt, int2* __restrict__ csr, int E) {
    int e = blockIdx.x * blockDim.x + threadIdx.x;
    if (e >= E) return;
    int d = edst[e];
    int r = atomicSub(&cnt[d], 1);
    csr[rowptr[d] + r - 1] = make_int2(esrc[e], __float_as_int(eval_[e]));
}

// ===========================================================================
// bf16 gather: one wave per node; 4 edge-groups x 16 lanes; lane loads 16 B
// (8 bf16 feats) per edge.  Cross-group __shfl_xor reduce, alpha-blend, write.
// ===========================================================================
__global__ __launch_bounds__(256) void k_gather16(
    const unsigned short* __restrict__ in16, const int2* __restrict__ csr,
    const int* __restrict__ rowptr, const float* __restrict__ h0,
    const float* __restrict__ alpha, float* __restrict__ out, int N)
{
    int w = (int)(((long long)blockIdx.x * blockDim.x + threadIdx.x) >> 6);
    if (w >= N) return;
    int lane = threadIdx.x & 63;
    int g = lane >> 4;      // edge group 0..3
    int s = lane & 15;      // feat slice: feats [8s, 8s+8)

    int beg = rowptr[w], end = rowptr[w + 1];

    float a0 = 0.f, a1 = 0.f, a2 = 0.f, a3 = 0.f;
    float a4 = 0.f, a5 = 0.f, a6 = 0.f, a7 = 0.f;

    for (int i = beg; i < end; i += 4) {
        int e = i + g;
        if (e < end) {
            int2 p = csr[e];
            float v = __int_as_float(p.y);
            const uint4 x = *reinterpret_cast<const uint4*>(
                &in16[(size_t)p.x * DFEAT + s * 8]);
            a0 = fmaf(v, __uint_as_float(x.x << 16),          a0);
            a1 = fmaf(v, __uint_as_float(x.x & 0xffff0000u),  a1);
            a2 = fmaf(v, __uint_as_float(x.y << 16),          a2);
            a3 = fmaf(v, __uint_as_float(x.y & 0xffff0000u),  a3);
            a4 = fmaf(v, __uint_as_float(x.z << 16),          a4);
            a5 = fmaf(v, __uint_as_float(x.z & 0xffff0000u),  a5);
            a6 = fmaf(v, __uint_as_float(x.w << 16),          a6);
            a7 = fmaf(v, __uint_as_float(x.w & 0xffff0000u),  a7);
        }
    }
    // reduce across the 4 edge groups (lane ^= 16, ^= 32)
    a0 += __shfl_xor(a0, 16); a0 += __shfl_xor(a0, 32);
    a1 += __shfl_xor(a1, 16); a1 += __shfl_xor(a1, 32);
    a2 += __shfl_xor(a2, 16); a2 += __shfl_xor(a2, 32);
    a3 += __shfl_xor(a3, 16); a3 += __shfl_xor(a3, 32);
    a4 += __shfl_xor(a4, 16); a4 += __shfl_xor(a4, 32);
    a5 += __shfl_xor(a5, 16); a5 += __shfl_xor(a5, 32);
    a6 += __shfl_xor(a6, 16); a6 += __shfl_xor(a6, 32);
    a7 += __shfl_xor(a7, 16); a7 += __shfl_xor(a7, 32);

    float a   = 0.5f / (1.0f + __expf(-alpha[0]));
    float oma = 1.0f - a;

    if (lane < 32) {
        int hi = lane >> 4;   // 0: feats 8s..8s+3,  1: feats 8s+4..8s+7
        float b0 = hi ? a4 : a0;
        float b1 = hi ? a5 : a1;
        float b2 = hi ? a6 : a2;
        float b3 = hi ? a7 : a3;
        size_t base = (size_t)w * DFEAT + s * 8 + hi * 4;
        float4 h0v = *reinterpret_cast<const float4*>(&h0[base]);
        float4 sv;
        sv.x = oma * b0 + a * h0v.x;
        sv.y = oma * b1 + a * h0v.y;
        sv.z = oma * b2 + a * h0v.z;
        sv.w = oma * b3 + a * h0v.w;
        *reinterpret_cast<float4*>(&out[base]) = sv;
    }
}

// ===========================================================================
// f32 gather (fallback plan B) — one wave per node, 2 feats/lane
// ===========================================================================
__global__ __launch_bounds__(256) void k_gather(
    const float* __restrict__ input, const int2* __restrict__ csr,
    const int* __restrict__ rowptr, const float* __restrict__ h0,
    const float* __restrict__ alpha, float* __restrict__ out, int N)
{
    int w    = (int)(((long long)blockIdx.x * blockDim.x + threadIdx.x) >> 6);
    int lane = threadIdx.x & 63;
    if (w >= N) return;
    int beg = rowptr[w], end = rowptr[w + 1];
    float ax = 0.f, ay = 0.f, bx = 0.f, by = 0.f;
    int i = beg;
    for (; i + 2 <= end; i += 2) {
        int2 p0 = csr[i], p1 = csr[i + 1];
        float2 x0 = *(const float2*)&input[(size_t)p0.x * DFEAT + lane * 2];
        float2 x1 = *(const float2*)&input[(size_t)p1.x * DFEAT + lane * 2];
        float v0 = __int_as_float(p0.y), v1 = __int_as_float(p1.y);
        ax = fmaf(v0, x0.x, ax); ay = fmaf(v0, x0.y, ay);
        bx = fmaf(v1, x1.x, bx); by = fmaf(v1, x1.y, by);
    }
    if (i < end) {
        int2 p = csr[i];
        float2 x = *(const float2*)&input[(size_t)p.x * DFEAT + lane * 2];
        float v = __int_as_float(p.y);
        ax = fmaf(v, x.x, ax); ay = fmaf(v, x.y, ay);
    }
    float hx = ax + bx, hy = ay + by;
    float a   = 0.5f / (1.0f + __expf(-alpha[0]));
    float oma = 1.0f - a;
    float2 h0v = *(const float2*)&h0[(size_t)w * DFEAT + lane * 2];
    float2 sv;
    sv.x = oma * hx + a * h0v.x;
    sv.y = oma * hy + a * h0v.y;
    *(float2*)&out[(size_t)w * DFEAT + lane * 2] = sv;
}

// ===========================================================================
// Fallback scatter (atomic) — plan C
// ===========================================================================
__global__ __launch_bounds__(256) void gcn_scatter(
    const float* __restrict__ input, const int* __restrict__ esrc,
    const int* __restrict__ edst, const float* __restrict__ eval_,
    float* __restrict__ hi, int E)
{
    long long t = (long long)blockIdx.x * blockDim.x + threadIdx.x;
    int e = (int)(t >> 6);
    if (e >= E) return;
    int lane = (int)(t & 63);
    int s = esrc[e]; int d = edst[e]; float v = eval_[e];
    const float2 x = *reinterpret_cast<const float2*>(&input[(size_t)s * DFEAT + lane * 2]);
    float* p = &hi[(size_t)d * DFEAT + lane * 2];
    unsafeAtomicAdd(p,     x.x * v);
    unsafeAtomicAdd(p + 1, x.y * v);
}

// ===========================================================================
// Epilogue: out = S @ W' + input, W' = THETA*W + (1-THETA)*I (bf16 LDS).
// BLEND=true: out holds hi, blend with h0 first (plan C only).
// ===========================================================================
template <bool BLEND>
__global__ __launch_bounds__(256) void gcn_epilogue(
    float* __restrict__ out, const float* __restrict__ h0,
    const float* __restrict__ inp, const float* __restrict__ W,
    const float* __restrict__ alpha, int N)
{
    __shared__ __hip_bfloat16 Wl[DFEAT * DFEAT];   // 32 KB
    __shared__ float4 S4[16][DFEAT / 4];           // 8 KB

    const float a   = 0.5f / (1.0f + __expf(-alpha[0]));
    const float oma = 1.0f - a;

    for (int i = threadIdx.x; i < DFEAT * DFEAT; i += 256) {
        int k = i >> 7, j = i & 127;
        float w = W[i] * THETA;
        if (k == j) w += 1.0f - THETA;
        Wl[i] = __float2bfloat16(w);
    }

    const int j  = threadIdx.x & 127;
    const int rg = threadIdx.x >> 7;

    for (int base = blockIdx.x * 16; base < N; base += gridDim.x * 16) {
        const int rows = min(16, N - base);
        __syncthreads();
        for (int i = threadIdx.x; i < rows * 32; i += 256) {
            int r = i >> 5, c = i & 31;
            size_t g = (size_t)(base + r) * (DFEAT / 4) + c;
            float4 hv = reinterpret_cast<const float4*>(out)[g];
            float4 sv;
            if (BLEND) {
                float4 h0v = reinterpret_cast<const float4*>(h0)[g];
                sv.x = oma * hv.x + a * h0v.x;
                sv.y = oma * hv.y + a * h0v.y;
                sv.z = oma * hv.z + a * h0v.z;
                sv.w = oma * hv.w + a * h0v.w;
            } else {
                sv = hv;
            }
            S4[r][c] = sv;
        }
        __syncthreads();

        float acc[8];
        #pragma unroll
        for (int r = 0; r < 8; r++) acc[r] = 0.0f;
        for (int k = 0; k < DFEAT; k += 4) {
            float w0 = __bfloat162float(Wl[(k + 0) * DFEAT + j]);
            float w1 = __bfloat162float(Wl[(k + 1) * DFEAT + j]);
            float w2 = __bfloat162float(Wl[(k + 2) * DFEAT + j]);
            float w3 = __bfloat162float(Wl[(k + 3) * DFEAT + j]);
            #pragma unroll
            for (int r = 0; r < 8; r++) {
                float4 s4 = S4[rg * 8 + r][k >> 2];
                acc[r] = fmaf(s4.x, w0, acc[r]);
                acc[r] = fmaf(s4.y, w1, acc[r]);
                acc[r] = fmaf(s4.z, w2, acc[r]);
                acc[r] = fmaf(s4.w, w3, acc[r]);
            }
        }
        #pragma unroll
        for (int r = 0; r < 8; r++) {
            int rr = rg * 8 + r;
            if (rr < rows) {
                size_t g = (size_t)(base + rr) * DFEAT + j;
                out[g] = acc[r] + inp[g];
            }
        }
    }
}

extern "C" void kernel_launch(void* const* d_in, const int* in_sizes, int n_in,
                              void* d_out, int out_size, void* d_ws, size_t ws_size,
                              hipStream_t stream) {
    const float* input = (const float*)d_in[0];
    const int*   esrc  = (const int*)  d_in[1];
    const int*   edst  = (const int*)  d_in[2];
    const float* eval_ = (const float*)d_in[3];
    const float* h0    = (const float*)d_in[4];
    const float* W     = (const float*)d_in[5];
    const float* alpha = (const float*)d_in[6];

    const int N = in_sizes[0] / DFEAT;
    const int E = in_sizes[1];
    float* out = (float*)d_out;
    const int B = (N + 255) / 256;   // scan blocks; must be <= 1024

    // ---- Plan A layout (bytes): in16[N*128*2] | csr[E*8] | rowptr | cnt | part
    size_t bA_in16   = 0;
    size_t bA_csr    = (bA_in16 + (size_t)N * DFEAT * 2 + 15) & ~(size_t)15;
    size_t bA_rowptr = bA_csr + (size_t)E * 8;
    size_t bA_cnt    = bA_rowptr + (size_t)(N + 1) * 4;
    size_t bA_part   = bA_cnt + (size_t)N * 4;
    size_t needA     = bA_part + 1024 * 4;

    // ---- Plan B layout (ints): rowptr[N+1] | cnt[N] | part[1024] | csr[E]
    size_t o_rowptr = 0;
    size_t o_cnt    = o_rowptr + (size_t)(N + 1);
    size_t o_part   = o_cnt + (size_t)N;
    size_t o_csr    = (o_part + 1024 + 1) & ~(size_t)1;
    size_t needB    = o_csr * 4 + (size_t)E * 8;

    if (ws_size >= needA && B <= 1024) {
        unsigned short* in16 = (unsigned short*)((char*)d_ws + bA_in16);
        int2* csr    = (int2*)((char*)d_ws + bA_csr);
        int*  rowptr = (int*) ((char*)d_ws + bA_rowptr);
        int*  cnt    = (int*) ((char*)d_ws + bA_cnt);
        int*  part   = (int*) ((char*)d_ws + bA_part);

        int n8 = N * DFEAT / 8;
        k_cvt  <<<dim3((n8 + 255) / 256), dim3(256), 0, stream>>>(input, (uint4*)in16, n8);
        hipMemsetAsync(cnt, 0, (size_t)N * sizeof(int), stream);
        k_hist <<<dim3((E + 255) / 256), dim3(256), 0, stream>>>(edst, cnt, E);
        k_scanA<<<dim3(B),               dim3(256), 0, stream>>>(cnt, part, N);
        k_scanB<<<dim3(1),               dim3(1024), 0, stream>>>(part, rowptr, B, N);
        k_scanC<<<dim3(B),               dim3(256), 0, stream>>>(cnt, part, rowptr, N);
        k_slot <<<dim3((E + 255) / 256), dim3(256), 0, stream>>>(esrc, edst, eval_,
                                                                 rowptr, cnt, csr, E);
        k_gather16<<<dim3((N + 3) / 4),  dim3(256), 0, stream>>>(in16, csr, rowptr,
                                                                 h0, alpha, out, N);
        gcn_epilogue<false><<<dim3(2048), dim3(256), 0, stream>>>(out, h0, input, W,
                                                                  alpha, N);
    } else if (ws_size >= needB && B <= 1024) {
        int*  rowptr = (int*)d_ws + o_rowptr;
        int*  cnt    = (int*)d_ws + o_cnt;
        int*  part   = (int*)d_ws + o_part;
        int2* csr    = (int2*)((int*)d_ws + o_csr);

        hipMemsetAsync(cnt, 0, (size_t)N * sizeof(int), stream);
        k_hist <<<dim3((E + 255) / 256), dim3(256), 0, stream>>>(edst, cnt, E);
        k_scanA<<<dim3(B),               dim3(256), 0, stream>>>(cnt, part, N);
        k_scanB<<<dim3(1),               dim3(1024), 0, stream>>>(part, rowptr, B, N);
        k_scanC<<<dim3(B),               dim3(256), 0, stream>>>(cnt, part, rowptr, N);
        k_slot <<<dim3((E + 255) / 256), dim3(256), 0, stream>>>(esrc, edst, eval_,
                                                                 rowptr, cnt, csr, E);
        k_gather<<<dim3((N + 3) / 4),    dim3(256), 0, stream>>>(input, csr, rowptr,
                                                                 h0, alpha, out, N);
        gcn_epilogue<false><<<dim3(2048), dim3(256), 0, stream>>>(out, h0, input, W,
                                                                  alpha, N);
    } else {
        hipMemsetAsync(out, 0, (size_t)N * DFEAT * sizeof(float), stream);
        long long threads = (long long)E * 64;
        unsigned  nblk    = (unsigned)((threads + 255) / 256);
        gcn_scatter<<<dim3(nblk), dim3(256), 0, stream>>>(input, esrc, edst, eval_, out, E);
        gcn_epilogue<true><<<dim3(2048), dim3(256), 0, stream>>>(out, h0, input, W,
                                                                 alpha, N);
    }
}

// Round 4
// 333.604 us; speedup vs baseline: 4.2717x; 1.1123x over previous
//
#include <hip/hip_runtime.h>
#include <hip/hip_bf16.h>

#define DFEAT 128
#define THETA 0.25f

typedef __attribute__((ext_vector_type(8))) short short8;
typedef __attribute__((ext_vector_type(4))) float f32x4;

__device__ inline unsigned short bf16_bits(float x) {
    __hip_bfloat16 h = __float2bfloat16(x);
    return *reinterpret_cast<unsigned short*>(&h);
}
__device__ inline unsigned pk_bf16(float x, float y) {
    return (unsigned)bf16_bits(x) | ((unsigned)bf16_bits(y) << 16);
}

// ===========================================================================
// Convert input rows to bf16 (one thread per 8 floats)
// ===========================================================================
__global__ __launch_bounds__(256) void k_cvt(const float* __restrict__ in,
                                             uint4* __restrict__ o, int n8) {
    int i = blockIdx.x * blockDim.x + threadIdx.x;
    if (i >= n8) return;
    float4 a = reinterpret_cast<const float4*>(in)[(size_t)i * 2];
    float4 b = reinterpret_cast<const float4*>(in)[(size_t)i * 2 + 1];
    uint4 r;
    r.x = pk_bf16(a.x, a.y);
    r.y = pk_bf16(a.z, a.w);
    r.z = pk_bf16(b.x, b.y);
    r.w = pk_bf16(b.z, b.w);
    o[i] = r;
}

// ===========================================================================
// CSR build: histogram -> 3-kernel exclusive scan -> slot scatter
// ===========================================================================
__global__ void k_hist(const int* __restrict__ edst, int* __restrict__ cnt, int E) {
    int e = blockIdx.x * blockDim.x + threadIdx.x;
    if (e < E) atomicAdd(&cnt[edst[e]], 1);
}

__global__ void k_scanA(const int* __restrict__ cnt, int* __restrict__ part, int N) {
    __shared__ int s[256];
    int i = blockIdx.x * 256 + threadIdx.x;
    s[threadIdx.x] = (i < N) ? cnt[i] : 0;
    __syncthreads();
    for (int off = 128; off > 0; off >>= 1) {
        if (threadIdx.x < off) s[threadIdx.x] += s[threadIdx.x + off];
        __syncthreads();
    }
    if (threadIdx.x == 0) part[blockIdx.x] = s[0];
}

__global__ void k_scanB(int* __restrict__ part, int* __restrict__ rowptr, int B, int N) {
    __shared__ int buf[1024];
    int t = threadIdx.x;
    buf[t] = (t < B) ? part[t] : 0;
    __syncthreads();
    for (int off = 1; off < 1024; off <<= 1) {
        int y = (t >= off) ? buf[t - off] : 0;
        __syncthreads();
        buf[t] += y;
        __syncthreads();
    }
    if (t < B) part[t] = (t == 0) ? 0 : buf[t - 1];
    if (t == B - 1) rowptr[N] = buf[t];
}

__global__ void k_scanC(const int* __restrict__ cnt, const int* __restrict__ part,
                        int* __restrict__ rowptr, int N) {
    __shared__ int buf[256];
    int t = threadIdx.x;
    int i = blockIdx.x * 256 + t;
    buf[t] = (i < N) ? cnt[i] : 0;
    __syncthreads();
    for (int off = 1; off < 256; off <<= 1) {
        int y = (t >= off) ? buf[t - off] : 0;
        __syncthreads();
        buf[t] += y;
        __syncthreads();
    }
    if (i < N) rowptr[i] = part[blockIdx.x] + ((t == 0) ? 0 : buf[t - 1]);
}

__global__ void k_slot(const int* __restrict__ esrc, const int* __restrict__ edst,
                       const float* __restrict__ eval_, const int* __restrict__ rowptr,
                       int* __restrict__ cnt, int2* __restrict__ csr, int E) {
    int e = blockIdx.x * blockDim.x + threadIdx.x;
    if (e >= E) return;
    int d = edst[e];
    int r = atomicSub(&cnt[d], 1);
    csr[rowptr[d] + r - 1] = make_int2(esrc[e], __float_as_int(eval_[e]));
}

// ===========================================================================
// Fused gather + MFMA epilogue.
// Per 16-row tile: 4 waves gather 4 nodes each (bf16 in16, 4 edge-groups x
// 16 lanes), alpha-blend with h0, write bf16 support rows to swizzled LDS A;
// then MFMA vs Wt = (THETA*W + (1-THETA)*I)^T (bf16, LDS, swizzled), add
// input residual, write f32 out.
// LDS swizzle: element k of row r lives at [r*128 + ((k>>3)^(r&7))*8 + (k&7)].
// Frag layouts (m97-verified structure): A: lane l = row l&15, k in
// [(l>>4)*8, +8);  B from Wt row n=l&15 same k-window;  D: col=l&15,
// row=(l>>4)*4+reg  [m89].
// ===========================================================================
__global__ __launch_bounds__(256) void k_fused(
    const unsigned short* __restrict__ in16, const int2* __restrict__ csr,
    const int* __restrict__ rowptr, const float* __restrict__ h0,
    const float* __restrict__ input, const float* __restrict__ W,
    const float* __restrict__ alpha, float* __restrict__ out,
    int N, int ntiles)
{
    __shared__ unsigned short Wt[DFEAT * DFEAT];   // 32 KB, Wt[n][k] swizzled
    __shared__ unsigned short At[16 * DFEAT];      // 4 KB, support tile

    const float a   = 0.5f / (1.0f + __expf(-alpha[0]));
    const float oma = 1.0f - a;

    // --- Stage Wt[n][k] = THETA*W[k][n] + (k==n)*(1-THETA) (bf16, swizzled)
    // Work item (kg, n): kg in [0,16), n in [0,128).  Reads coalesced along n;
    // writes one uint4 (8 bf16) -> conflict-free (slot spread via XOR).
    for (int item = threadIdx.x; item < 16 * DFEAT; item += 256) {
        int kg = item >> 7;          // k-group of 8
        int n  = item & 127;
        unsigned pk4[4];
        #pragma unroll
        for (int jj = 0; jj < 4; ++jj) {
            int k0 = kg * 8 + jj * 2;
            float w0 = THETA * W[(size_t)k0 * DFEAT + n];
            float w1 = THETA * W[(size_t)(k0 + 1) * DFEAT + n];
            if (k0 == n)     w0 += 1.0f - THETA;
            if (k0 + 1 == n) w1 += 1.0f - THETA;
            pk4[jj] = pk_bf16(w0, w1);
        }
        uint4 v = make_uint4(pk4[0], pk4[1], pk4[2], pk4[3]);
        int slot = kg ^ (n & 7);
        *reinterpret_cast<uint4*>(&Wt[n * DFEAT + slot * 8]) = v;
    }

    const int wv   = threadIdx.x >> 6;   // wave 0..3
    const int lane = threadIdx.x & 63;
    const int g    = lane >> 4;          // edge group 0..3
    const int s    = lane & 15;          // feat slice [8s, 8s+8)

    for (int tile = blockIdx.x; tile < ntiles; tile += gridDim.x) {
        const int row0 = tile * 16;
        __syncthreads();   // At free from prev MFMA reads; Wt ready (iter 0)

        #pragma unroll 1
        for (int q = 0; q < 4; ++q) {
            const int node = row0 + wv * 4 + q;
            float a0 = 0.f, a1 = 0.f, a2 = 0.f, a3 = 0.f;
            float a4 = 0.f, a5 = 0.f, a6 = 0.f, a7 = 0.f;
            if (node < N) {
                const int beg = rowptr[node], end = rowptr[node + 1];
                for (int i = beg; i < end; i += 4) {
                    int e = i + g;
                    if (e < end) {
                        int2 p = csr[e];
                        float v = __int_as_float(p.y);
                        const uint4 x = *reinterpret_cast<const uint4*>(
                            &in16[(size_t)p.x * DFEAT + s * 8]);
                        a0 = fmaf(v, __uint_as_float(x.x << 16),         a0);
                        a1 = fmaf(v, __uint_as_float(x.x & 0xffff0000u), a1);
                        a2 = fmaf(v, __uint_as_float(x.y << 16),         a2);
                        a3 = fmaf(v, __uint_as_float(x.y & 0xffff0000u), a3);
                        a4 = fmaf(v, __uint_as_float(x.z << 16),         a4);
                        a5 = fmaf(v, __uint_as_float(x.z & 0xffff0000u), a5);
                        a6 = fmaf(v, __uint_as_float(x.w << 16),         a6);
                        a7 = fmaf(v, __uint_as_float(x.w & 0xffff0000u), a7);
                    }
                }
            }
            a0 += __shfl_xor(a0, 16); a0 += __shfl_xor(a0, 32);
            a1 += __shfl_xor(a1, 16); a1 += __shfl_xor(a1, 32);
            a2 += __shfl_xor(a2, 16); a2 += __shfl_xor(a2, 32);
            a3 += __shfl_xor(a3, 16); a3 += __shfl_xor(a3, 32);
            a4 += __shfl_xor(a4, 16); a4 += __shfl_xor(a4, 32);
            a5 += __shfl_xor(a5, 16); a5 += __shfl_xor(a5, 32);
            a6 += __shfl_xor(a6, 16); a6 += __shfl_xor(a6, 32);
            a7 += __shfl_xor(a7, 16); a7 += __shfl_xor(a7, 32);

            if (lane < 32 && node < N) {
                int hi = lane >> 4;           // 0: feats 8s..+4, 1: 8s+4..+8
                float b0 = hi ? a4 : a0;
                float b1 = hi ? a5 : a1;
                float b2 = hi ? a6 : a2;
                float b3 = hi ? a7 : a3;
                size_t gb = (size_t)node * DFEAT + s * 8 + hi * 4;
                float4 h0v = *reinterpret_cast<const float4*>(&h0[gb]);
                b0 = oma * b0 + a * h0v.x;
                b1 = oma * b1 + a * h0v.y;
                b2 = oma * b2 + a * h0v.z;
                b3 = oma * b3 + a * h0v.w;
                int r = wv * 4 + q;
                uint2 pk;
                pk.x = pk_bf16(b0, b1);
                pk.y = pk_bf16(b2, b3);
                *reinterpret_cast<uint2*>(
                    &At[r * DFEAT + ((s ^ (r & 7)) << 3) + (hi << 2)]) = pk;
            }
        }
        __syncthreads();

        // --- MFMA phase: wave wv owns output cols [wv*32, wv*32+32)
        f32x4 acc0 = {0.f, 0.f, 0.f, 0.f};
        f32x4 acc1 = {0.f, 0.f, 0.f, 0.f};
        const int m  = lane & 15;
        const int kb = lane >> 4;
        const int n1 = wv * 32 + m;
        const int n2 = n1 + 16;
        #pragma unroll
        for (int kk = 0; kk < 4; ++kk) {
            short8 af = *reinterpret_cast<const short8*>(
                &At[m * DFEAT + (((kk * 4 + kb) ^ (m & 7)) << 3)]);
            short8 bf1 = *reinterpret_cast<const short8*>(
                &Wt[n1 * DFEAT + (((kk * 4 + kb) ^ (n1 & 7)) << 3)]);
            short8 bf2 = *reinterpret_cast<const short8*>(
                &Wt[n2 * DFEAT + (((kk * 4 + kb) ^ (n2 & 7)) << 3)]);
            acc0 = __builtin_amdgcn_mfma_f32_16x16x32_bf16(af, bf1, acc0, 0, 0, 0);
            acc1 = __builtin_amdgcn_mfma_f32_16x16x32_bf16(af, bf2, acc1, 0, 0, 0);
        }

        // --- Write out = D + input  (D: col=lane&15, row=(lane>>4)*4+reg)
        #pragma unroll
        for (int q = 0; q < 4; ++q) {
            int row = row0 + kb * 4 + q;
            if (row < N) {
                size_t gi = (size_t)row * DFEAT + n1;
                out[gi]      = acc0[q] + input[gi];
                out[gi + 16] = acc1[q] + input[gi + 16];
            }
        }
    }
}

// ===========================================================================
// f32 gather (fallback plan B) — one wave per node, 2 feats/lane
// ===========================================================================
__global__ __launch_bounds__(256) void k_gather(
    const float* __restrict__ input, const int2* __restrict__ csr,
    const int* __restrict__ rowptr, const float* __restrict__ h0,
    const float* __restrict__ alpha, float* __restrict__ out, int N)
{
    int w    = (int)(((long long)blockIdx.x * blockDim.x + threadIdx.x) >> 6);
    int lane = threadIdx.x & 63;
    if (w >= N) return;
    int beg = rowptr[w], end = rowptr[w + 1];
    float ax = 0.f, ay = 0.f, bx = 0.f, by = 0.f;
    int i = beg;
    for (; i + 2 <= end; i += 2) {
        int2 p0 = csr[i], p1 = csr[i + 1];
        float2 x0 = *(const float2*)&input[(size_t)p0.x * DFEAT + lane * 2];
        float2 x1 = *(const float2*)&input[(size_t)p1.x * DFEAT + lane * 2];
        float v0 = __int_as_float(p0.y), v1 = __int_as_float(p1.y);
        ax = fmaf(v0, x0.x, ax); ay = fmaf(v0, x0.y, ay);
        bx = fmaf(v1, x1.x, bx); by = fmaf(v1, x1.y, by);
    }
    if (i < end) {
        int2 p = csr[i];
        float2 x = *(const float2*)&input[(size_t)p.x * DFEAT + lane * 2];
        float v = __int_as_float(p.y);
        ax = fmaf(v, x.x, ax); ay = fmaf(v, x.y, ay);
    }
    float hx = ax + bx, hy = ay + by;
    float a   = 0.5f / (1.0f + __expf(-alpha[0]));
    float oma = 1.0f - a;
    float2 h0v = *(const float2*)&h0[(size_t)w * DFEAT + lane * 2];
    float2 sv;
    sv.x = oma * hx + a * h0v.x;
    sv.y = oma * hy + a * h0v.y;
    *(float2*)&out[(size_t)w * DFEAT + lane * 2] = sv;
}

// ===========================================================================
// Fallback scatter (atomic) — plan C
// ===========================================================================
__global__ __launch_bounds__(256) void gcn_scatter(
    const float* __restrict__ input, const int* __restrict__ esrc,
    const int* __restrict__ edst, const float* __restrict__ eval_,
    float* __restrict__ hi, int E)
{
    long long t = (long long)blockIdx.x * blockDim.x + threadIdx.x;
    int e = (int)(t >> 6);
    if (e >= E) return;
    int lane = (int)(t & 63);
    int s = esrc[e]; int d = edst[e]; float v = eval_[e];
    const float2 x = *reinterpret_cast<const float2*>(&input[(size_t)s * DFEAT + lane * 2]);
    float* p = &hi[(size_t)d * DFEAT + lane * 2];
    unsafeAtomicAdd(p,     x.x * v);
    unsafeAtomicAdd(p + 1, x.y * v);
}

// ===========================================================================
// VALU epilogue (plans B/C): out = S @ W' + input
// ===========================================================================
template <bool BLEND>
__global__ __launch_bounds__(256) void gcn_epilogue(
    float* __restrict__ out, const float* __restrict__ h0,
    const float* __restrict__ inp, const float* __restrict__ W,
    const float* __restrict__ alpha, int N)
{
    __shared__ __hip_bfloat16 Wl[DFEAT * DFEAT];
    __shared__ float4 S4[16][DFEAT / 4];

    const float a   = 0.5f / (1.0f + __expf(-alpha[0]));
    const float oma = 1.0f - a;

    for (int i = threadIdx.x; i < DFEAT * DFEAT; i += 256) {
        int k = i >> 7, j = i & 127;
        float w = W[i] * THETA;
        if (k == j) w += 1.0f - THETA;
        Wl[i] = __float2bfloat16(w);
    }

    const int j  = threadIdx.x & 127;
    const int rg = threadIdx.x >> 7;

    for (int base = blockIdx.x * 16; base < N; base += gridDim.x * 16) {
        const int rows = min(16, N - base);
        __syncthreads();
        for (int i = threadIdx.x; i < rows * 32; i += 256) {
            int r = i >> 5, c = i & 31;
            size_t gph = (size_t)(base + r) * (DFEAT / 4) + c;
            float4 hv = reinterpret_cast<const float4*>(out)[gph];
            float4 sv;
            if (BLEND) {
                float4 h0v = reinterpret_cast<const float4*>(h0)[gph];
                sv.x = oma * hv.x + a * h0v.x;
                sv.y = oma * hv.y + a * h0v.y;
                sv.z = oma * hv.z + a * h0v.z;
                sv.w = oma * hv.w + a * h0v.w;
            } else {
                sv = hv;
            }
            S4[r][c] = sv;
        }
        __syncthreads();

        float acc[8];
        #pragma unroll
        for (int r = 0; r < 8; r++) acc[r] = 0.0f;
        for (int k = 0; k < DFEAT; k += 4) {
            float w0 = __bfloat162float(Wl[(k + 0) * DFEAT + j]);
            float w1 = __bfloat162float(Wl[(k + 1) * DFEAT + j]);
            float w2 = __bfloat162float(Wl[(k + 2) * DFEAT + j]);
            float w3 = __bfloat162float(Wl[(k + 3) * DFEAT + j]);
            #pragma unroll
            for (int r = 0; r < 8; r++) {
                float4 s4 = S4[rg * 8 + r][k >> 2];
                acc[r] = fmaf(s4.x, w0, acc[r]);
                acc[r] = fmaf(s4.y, w1, acc[r]);
                acc[r] = fmaf(s4.z, w2, acc[r]);
                acc[r] = fmaf(s4.w, w3, acc[r]);
            }
        }
        #pragma unroll
        for (int r = 0; r < 8; r++) {
            int rr = rg * 8 + r;
            if (rr < rows) {
                size_t gph = (size_t)(base + rr) * DFEAT + j;
                out[gph] = acc[r] + inp[gph];
            }
        }
    }
}

extern "C" void kernel_launch(void* const* d_in, const int* in_sizes, int n_in,
                              void* d_out, int out_size, void* d_ws, size_t ws_size,
                              hipStream_t stream) {
    const float* input = (const float*)d_in[0];
    const int*   esrc  = (const int*)  d_in[1];
    const int*   edst  = (const int*)  d_in[2];
    const float* eval_ = (const float*)d_in[3];
    const float* h0    = (const float*)d_in[4];
    const float* W     = (const float*)d_in[5];
    const float* alpha = (const float*)d_in[6];

    const int N = in_sizes[0] / DFEAT;
    const int E = in_sizes[1];
    float* out = (float*)d_out;
    const int B = (N + 255) / 256;

    // ---- Plan A layout (bytes): in16[N*128*2] | csr[E*8] | rowptr | cnt | part
    size_t bA_in16   = 0;
    size_t bA_csr    = (bA_in16 + (size_t)N * DFEAT * 2 + 15) & ~(size_t)15;
    size_t bA_rowptr = bA_csr + (size_t)E * 8;
    size_t bA_cnt    = bA_rowptr + (size_t)(N + 1) * 4;
    size_t bA_part   = bA_cnt + (size_t)N * 4;
    size_t needA     = bA_part + 1024 * 4;

    // ---- Plan B layout (ints): rowptr[N+1] | cnt[N] | part[1024] | csr[E]
    size_t o_rowptr = 0;
    size_t o_cnt    = o_rowptr + (size_t)(N + 1);
    size_t o_part   = o_cnt + (size_t)N;
    size_t o_csr    = (o_part + 1024 + 1) & ~(size_t)1;
    size_t needB    = o_csr * 4 + (size_t)E * 8;

    if (ws_size >= needA && B <= 1024) {
        unsigned short* in16 = (unsigned short*)((char*)d_ws + bA_in16);
        int2* csr    = (int2*)((char*)d_ws + bA_csr);
        int*  rowptr = (int*) ((char*)d_ws + bA_rowptr);
        int*  cnt    = (int*) ((char*)d_ws + bA_cnt);
        int*  part   = (int*) ((char*)d_ws + bA_part);

        int n8 = N * DFEAT / 8;
        int ntiles = (N + 15) / 16;
        k_cvt  <<<dim3((n8 + 255) / 256), dim3(256), 0, stream>>>(input, (uint4*)in16, n8);
        hipMemsetAsync(cnt, 0, (size_t)N * sizeof(int), stream);
        k_hist <<<dim3((E + 255) / 256), dim3(256), 0, stream>>>(edst, cnt, E);
        k_scanA<<<dim3(B),               dim3(256), 0, stream>>>(cnt, part, N);
        k_scanB<<<dim3(1),               dim3(1024), 0, stream>>>(part, rowptr, B, N);
        k_scanC<<<dim3(B),               dim3(256), 0, stream>>>(cnt, part, rowptr, N);
        k_slot <<<dim3((E + 255) / 256), dim3(256), 0, stream>>>(esrc, edst, eval_,
                                                                 rowptr, cnt, csr, E);
        k_fused<<<dim3(2048),            dim3(256), 0, stream>>>(in16, csr, rowptr,
                                                                 h0, input, W, alpha,
                                                                 out, N, ntiles);
    } else if (ws_size >= needB && B <= 1024) {
        int*  rowptr = (int*)d_ws + o_rowptr;
        int*  cnt    = (int*)d_ws + o_cnt;
        int*  part   = (int*)d_ws + o_part;
        int2* csr    = (int2*)((int*)d_ws + o_csr);

        hipMemsetAsync(cnt, 0, (size_t)N * sizeof(int), stream);
        k_hist <<<dim3((E + 255) / 256), dim3(256), 0, stream>>>(edst, cnt, E);
        k_scanA<<<dim3(B),               dim3(256), 0, stream>>>(cnt, part, N);
        k_scanB<<<dim3(1),               dim3(1024), 0, stream>>>(part, rowptr, B, N);
        k_scanC<<<dim3(B),               dim3(256), 0, stream>>>(cnt, part, rowptr, N);
        k_slot <<<dim3((E + 255) / 256), dim3(256), 0, stream>>>(esrc, edst, eval_,
                                                                 rowptr, cnt, csr, E);
        k_gather<<<dim3((N + 3) / 4),    dim3(256), 0, stream>>>(input, csr, rowptr,
                                                                 h0, alpha, out, N);
        gcn_epilogue<false><<<dim3(2048), dim3(256), 0, stream>>>(out, h0, input, W,
                                                                  alpha, N);
    } else {
        hipMemsetAsync(out, 0, (size_t)N * DFEAT * sizeof(float), stream);
        long long threads = (long long)E * 64;
        unsigned  nblk    = (unsigned)((threads + 255) / 256);
        gcn_scatter<<<dim3(nblk), dim3(256), 0, stream>>>(input, esrc, edst, eval_, out, E);
        gcn_epilogue<true><<<dim3(2048), dim3(256), 0, stream>>>(out, h0, input, W,
                                                                 alpha, N);
    }
}

// Round 5
// 304.610 us; speedup vs baseline: 4.6783x; 1.0952x over previous
//
#include <hip/hip_runtime.h>
#include <hip/hip_bf16.h>

#define DFEAT 128
#define THETA 0.25f

typedef __attribute__((ext_vector_type(8))) short short8;
typedef __attribute__((ext_vector_type(4))) float f32x4;

__device__ inline unsigned short bf16_bits(float x) {
    __hip_bfloat16 h = __float2bfloat16(x);
    return *reinterpret_cast<unsigned short*>(&h);
}
__device__ inline unsigned pk_bf16(float x, float y) {
    return (unsigned)bf16_bits(x) | ((unsigned)bf16_bits(y) << 16);
}

// ===========================================================================
// Convert input rows to bf16 (one thread per 8 floats)
// ===========================================================================
__global__ __launch_bounds__(256) void k_cvt(const float* __restrict__ in,
                                             uint4* __restrict__ o, int n8) {
    int i = blockIdx.x * blockDim.x + threadIdx.x;
    if (i >= n8) return;
    float4 a = reinterpret_cast<const float4*>(in)[(size_t)i * 2];
    float4 b = reinterpret_cast<const float4*>(in)[(size_t)i * 2 + 1];
    uint4 r;
    r.x = pk_bf16(a.x, a.y);
    r.y = pk_bf16(a.z, a.w);
    r.z = pk_bf16(b.x, b.y);
    r.w = pk_bf16(b.z, b.w);
    o[i] = r;
}

// ===========================================================================
// Prepare W' = (THETA*W + (1-THETA)*I)^T as bf16, pre-swizzled LDS-image:
// element k of row n lives at wprep[n*128 + ((k>>3)^(n&7))*8 + (k&7)].
// ===========================================================================
__global__ __launch_bounds__(256) void k_wprep(const float* __restrict__ W,
                                               unsigned short* __restrict__ wp) {
    int item = blockIdx.x * blockDim.x + threadIdx.x;   // 16*128 items
    if (item >= 16 * DFEAT) return;
    int kg = item >> 7;          // k-group of 8
    int n  = item & 127;
    unsigned pk4[4];
    #pragma unroll
    for (int jj = 0; jj < 4; ++jj) {
        int k0 = kg * 8 + jj * 2;
        float w0 = THETA * W[(size_t)k0 * DFEAT + n];
        float w1 = THETA * W[(size_t)(k0 + 1) * DFEAT + n];
        if (k0 == n)     w0 += 1.0f - THETA;
        if (k0 + 1 == n) w1 += 1.0f - THETA;
        pk4[jj] = pk_bf16(w0, w1);
    }
    uint4 v = make_uint4(pk4[0], pk4[1], pk4[2], pk4[3]);
    int slot = kg ^ (n & 7);
    *reinterpret_cast<uint4*>(&wp[n * DFEAT + slot * 8]) = v;
}

// ===========================================================================
// CSR build: histogram -> 3-kernel exclusive scan -> slot scatter
// ===========================================================================
__global__ void k_hist(const int* __restrict__ edst, int* __restrict__ cnt, int E) {
    int i = blockIdx.x * blockDim.x + threadIdx.x;
    int e4 = i * 4;
    if (e4 + 4 <= E) {
        int4 d = *reinterpret_cast<const int4*>(&edst[e4]);
        atomicAdd(&cnt[d.x], 1);
        atomicAdd(&cnt[d.y], 1);
        atomicAdd(&cnt[d.z], 1);
        atomicAdd(&cnt[d.w], 1);
    } else {
        for (int e = e4; e < E; ++e) atomicAdd(&cnt[edst[e]], 1);
    }
}

__global__ void k_scanA(const int* __restrict__ cnt, int* __restrict__ part, int N) {
    __shared__ int s[256];
    int i = blockIdx.x * 256 + threadIdx.x;
    s[threadIdx.x] = (i < N) ? cnt[i] : 0;
    __syncthreads();
    for (int off = 128; off > 0; off >>= 1) {
        if (threadIdx.x < off) s[threadIdx.x] += s[threadIdx.x + off];
        __syncthreads();
    }
    if (threadIdx.x == 0) part[blockIdx.x] = s[0];
}

__global__ void k_scanB(int* __restrict__ part, int* __restrict__ rowptr, int B, int N) {
    __shared__ int buf[1024];
    int t = threadIdx.x;
    buf[t] = (t < B) ? part[t] : 0;
    __syncthreads();
    for (int off = 1; off < 1024; off <<= 1) {
        int y = (t >= off) ? buf[t - off] : 0;
        __syncthreads();
        buf[t] += y;
        __syncthreads();
    }
    if (t < B) part[t] = (t == 0) ? 0 : buf[t - 1];
    if (t == B - 1) rowptr[N] = buf[t];
}

__global__ void k_scanC(const int* __restrict__ cnt, const int* __restrict__ part,
                        int* __restrict__ rowptr, int N) {
    __shared__ int buf[256];
    int t = threadIdx.x;
    int i = blockIdx.x * 256 + t;
    buf[t] = (i < N) ? cnt[i] : 0;
    __syncthreads();
    for (int off = 1; off < 256; off <<= 1) {
        int y = (t >= off) ? buf[t - off] : 0;
        __syncthreads();
        buf[t] += y;
        __syncthreads();
    }
    if (i < N) rowptr[i] = part[blockIdx.x] + ((t == 0) ? 0 : buf[t - 1]);
}

__global__ void k_slot(const int* __restrict__ esrc, const int* __restrict__ edst,
                       const float* __restrict__ eval_, const int* __restrict__ rowptr,
                       int* __restrict__ cnt, int2* __restrict__ csr, int E) {
    int i = blockIdx.x * blockDim.x + threadIdx.x;
    int e4 = i * 4;
    if (e4 + 4 <= E) {
        int4   s = *reinterpret_cast<const int4*>(&esrc[e4]);
        int4   d = *reinterpret_cast<const int4*>(&edst[e4]);
        float4 v = *reinterpret_cast<const float4*>(&eval_[e4]);
        int r;
        r = atomicSub(&cnt[d.x], 1); csr[rowptr[d.x] + r - 1] = make_int2(s.x, __float_as_int(v.x));
        r = atomicSub(&cnt[d.y], 1); csr[rowptr[d.y] + r - 1] = make_int2(s.y, __float_as_int(v.y));
        r = atomicSub(&cnt[d.z], 1); csr[rowptr[d.z] + r - 1] = make_int2(s.z, __float_as_int(v.z));
        r = atomicSub(&cnt[d.w], 1); csr[rowptr[d.w] + r - 1] = make_int2(s.w, __float_as_int(v.w));
    } else {
        for (int e = e4; e < E; ++e) {
            int d = edst[e];
            int r = atomicSub(&cnt[d], 1);
            csr[rowptr[d] + r - 1] = make_int2(esrc[e], __float_as_int(eval_[e]));
        }
    }
}

// ===========================================================================
// Fused gather + MFMA epilogue, v2: W' fragments in REGISTERS (loaded once
// from pre-swizzled global image), LDS = 4 KB At tile only -> high occupancy.
// Per 16-row tile: 4 waves gather 4 nodes each (4 edge-groups x 16 lanes),
// alpha-blend, write bf16 support rows to swizzled LDS At; barrier; each wave
// MFMAs its 32 output cols; nontemporal residual add + store.
// Frag layouts (m89/m97-verified): A: lane l = row l&15, k in [(l>>4)*8,+8);
// B: lane l = col l&15, same k-window; D: col=l&15, row=(l>>4)*4+reg.
// ===========================================================================
__global__ __launch_bounds__(256) void k_fused2(
    const unsigned short* __restrict__ in16, const int2* __restrict__ csr,
    const int* __restrict__ rowptr, const float* __restrict__ h0,
    const float* __restrict__ input, const unsigned short* __restrict__ wp,
    const float* __restrict__ alpha, float* __restrict__ out,
    int N, int ntiles)
{
    __shared__ unsigned short At[16 * DFEAT];      // 4 KB, support tile

    const float a   = 0.5f / (1.0f + __expf(-alpha[0]));
    const float oma = 1.0f - a;

    const int wv   = threadIdx.x >> 6;   // wave 0..3
    const int lane = threadIdx.x & 63;
    const int g    = lane >> 4;          // edge group 0..3
    const int s    = lane & 15;          // feat slice [8s, 8s+8)
    const int m    = lane & 15;
    const int kb   = lane >> 4;
    const int n1   = wv * 32 + m;        // wave owns cols [wv*32, wv*32+32)
    const int n2   = n1 + 16;

    // --- Load B-fragments into registers (L2-resident, once per block)
    short8 bw1[4], bw2[4];
    #pragma unroll
    for (int kk = 0; kk < 4; ++kk) {
        int w = kk * 4 + kb;
        bw1[kk] = *reinterpret_cast<const short8*>(
            &wp[n1 * DFEAT + ((w ^ (n1 & 7)) << 3)]);
        bw2[kk] = *reinterpret_cast<const short8*>(
            &wp[n2 * DFEAT + ((w ^ (n2 & 7)) << 3)]);
    }

    for (int tile = blockIdx.x; tile < ntiles; tile += gridDim.x) {
        const int row0 = tile * 16;
        __syncthreads();   // At free from prev iter's MFMA reads

        #pragma unroll 1
        for (int q = 0; q < 4; ++q) {
            const int node = row0 + wv * 4 + q;
            float a0 = 0.f, a1 = 0.f, a2 = 0.f, a3 = 0.f;
            float a4 = 0.f, a5 = 0.f, a6 = 0.f, a7 = 0.f;
            if (node < N) {
                const int beg = rowptr[node], end = rowptr[node + 1];
                for (int i = beg; i < end; i += 4) {
                    int e = i + g;
                    if (e < end) {
                        int2 p = csr[e];
                        float v = __int_as_float(p.y);
                        const uint4 x = *reinterpret_cast<const uint4*>(
                            &in16[(size_t)p.x * DFEAT + s * 8]);
                        a0 = fmaf(v, __uint_as_float(x.x << 16),         a0);
                        a1 = fmaf(v, __uint_as_float(x.x & 0xffff0000u), a1);
                        a2 = fmaf(v, __uint_as_float(x.y << 16),         a2);
                        a3 = fmaf(v, __uint_as_float(x.y & 0xffff0000u), a3);
                        a4 = fmaf(v, __uint_as_float(x.z << 16),         a4);
                        a5 = fmaf(v, __uint_as_float(x.z & 0xffff0000u), a5);
                        a6 = fmaf(v, __uint_as_float(x.w << 16),         a6);
                        a7 = fmaf(v, __uint_as_float(x.w & 0xffff0000u), a7);
                    }
                }
            }
            a0 += __shfl_xor(a0, 16); a0 += __shfl_xor(a0, 32);
            a1 += __shfl_xor(a1, 16); a1 += __shfl_xor(a1, 32);
            a2 += __shfl_xor(a2, 16); a2 += __shfl_xor(a2, 32);
            a3 += __shfl_xor(a3, 16); a3 += __shfl_xor(a3, 32);
            a4 += __shfl_xor(a4, 16); a4 += __shfl_xor(a4, 32);
            a5 += __shfl_xor(a5, 16); a5 += __shfl_xor(a5, 32);
            a6 += __shfl_xor(a6, 16); a6 += __shfl_xor(a6, 32);
            a7 += __shfl_xor(a7, 16); a7 += __shfl_xor(a7, 32);

            if (lane < 32 && node < N) {
                int hi = lane >> 4;           // 0: feats 8s..+4, 1: 8s+4..+8
                float b0 = hi ? a4 : a0;
                float b1 = hi ? a5 : a1;
                float b2 = hi ? a6 : a2;
                float b3 = hi ? a7 : a3;
                size_t gb = (size_t)node * DFEAT + s * 8 + hi * 4;
                float4 h0v = *reinterpret_cast<const float4*>(&h0[gb]);
                b0 = oma * b0 + a * h0v.x;
                b1 = oma * b1 + a * h0v.y;
                b2 = oma * b2 + a * h0v.z;
                b3 = oma * b3 + a * h0v.w;
                int r = wv * 4 + q;
                uint2 pk;
                pk.x = pk_bf16(b0, b1);
                pk.y = pk_bf16(b2, b3);
                *reinterpret_cast<uint2*>(
                    &At[r * DFEAT + ((s ^ (r & 7)) << 3) + (hi << 2)]) = pk;
            }
        }
        __syncthreads();

        // --- MFMA phase: wave wv computes cols [wv*32, wv*32+32)
        f32x4 acc0 = {0.f, 0.f, 0.f, 0.f};
        f32x4 acc1 = {0.f, 0.f, 0.f, 0.f};
        #pragma unroll
        for (int kk = 0; kk < 4; ++kk) {
            short8 af = *reinterpret_cast<const short8*>(
                &At[m * DFEAT + (((kk * 4 + kb) ^ (m & 7)) << 3)]);
            acc0 = __builtin_amdgcn_mfma_f32_16x16x32_bf16(af, bw1[kk], acc0, 0, 0, 0);
            acc1 = __builtin_amdgcn_mfma_f32_16x16x32_bf16(af, bw2[kk], acc1, 0, 0, 0);
        }

        // --- Write out = D + input  (D: col=lane&15, row=(lane>>4)*4+reg)
        #pragma unroll
        for (int q = 0; q < 4; ++q) {
            int row = row0 + kb * 4 + q;
            if (row < N) {
                size_t gi = (size_t)row * DFEAT + n1;
                float r0 = __builtin_nontemporal_load(&input[gi]);
                float r1 = __builtin_nontemporal_load(&input[gi + 16]);
                __builtin_nontemporal_store(acc0[q] + r0, &out[gi]);
                __builtin_nontemporal_store(acc1[q] + r1, &out[gi + 16]);
            }
        }
    }
}

// ===========================================================================
// f32 gather (fallback plan B) — one wave per node, 2 feats/lane
// ===========================================================================
__global__ __launch_bounds__(256) void k_gather(
    const float* __restrict__ input, const int2* __restrict__ csr,
    const int* __restrict__ rowptr, const float* __restrict__ h0,
    const float* __restrict__ alpha, float* __restrict__ out, int N)
{
    int w    = (int)(((long long)blockIdx.x * blockDim.x + threadIdx.x) >> 6);
    int lane = threadIdx.x & 63;
    if (w >= N) return;
    int beg = rowptr[w], end = rowptr[w + 1];
    float ax = 0.f, ay = 0.f, bx = 0.f, by = 0.f;
    int i = beg;
    for (; i + 2 <= end; i += 2) {
        int2 p0 = csr[i], p1 = csr[i + 1];
        float2 x0 = *(const float2*)&input[(size_t)p0.x * DFEAT + lane * 2];
        float2 x1 = *(const float2*)&input[(size_t)p1.x * DFEAT + lane * 2];
        float v0 = __int_as_float(p0.y), v1 = __int_as_float(p1.y);
        ax = fmaf(v0, x0.x, ax); ay = fmaf(v0, x0.y, ay);
        bx = fmaf(v1, x1.x, bx); by = fmaf(v1, x1.y, by);
    }
    if (i < end) {
        int2 p = csr[i];
        float2 x = *(const float2*)&input[(size_t)p.x * DFEAT + lane * 2];
        float v = __int_as_float(p.y);
        ax = fmaf(v, x.x, ax); ay = fmaf(v, x.y, ay);
    }
    float hx = ax + bx, hy = ay + by;
    float a   = 0.5f / (1.0f + __expf(-alpha[0]));
    float oma = 1.0f - a;
    float2 h0v = *(const float2*)&h0[(size_t)w * DFEAT + lane * 2];
    float2 sv;
    sv.x = oma * hx + a * h0v.x;
    sv.y = oma * hy + a * h0v.y;
    *(float2*)&out[(size_t)w * DFEAT + lane * 2] = sv;
}

// ===========================================================================
// Fallback scatter (atomic) — plan C
// ===========================================================================
__global__ __launch_bounds__(256) void gcn_scatter(
    const float* __restrict__ input, const int* __restrict__ esrc,
    const int* __restrict__ edst, const float* __restrict__ eval_,
    float* __restrict__ hi, int E)
{
    long long t = (long long)blockIdx.x * blockDim.x + threadIdx.x;
    int e = (int)(t >> 6);
    if (e >= E) return;
    int lane = (int)(t & 63);
    int s = esrc[e]; int d = edst[e]; float v = eval_[e];
    const float2 x = *reinterpret_cast<const float2*>(&input[(size_t)s * DFEAT + lane * 2]);
    float* p = &hi[(size_t)d * DFEAT + lane * 2];
    unsafeAtomicAdd(p,     x.x * v);
    unsafeAtomicAdd(p + 1, x.y * v);
}

// ===========================================================================
// VALU epilogue (plans B/C): out = S @ W' + input
// ===========================================================================
template <bool BLEND>
__global__ __launch_bounds__(256) void gcn_epilogue(
    float* __restrict__ out, const float* __restrict__ h0,
    const float* __restrict__ inp, const float* __restrict__ W,
    const float* __restrict__ alpha, int N)
{
    __shared__ __hip_bfloat16 Wl[DFEAT * DFEAT];
    __shared__ float4 S4[16][DFEAT / 4];

    const float a   = 0.5f / (1.0f + __expf(-alpha[0]));
    const float oma = 1.0f - a;

    for (int i = threadIdx.x; i < DFEAT * DFEAT; i += 256) {
        int k = i >> 7, j = i & 127;
        float w = W[i] * THETA;
        if (k == j) w += 1.0f - THETA;
        Wl[i] = __float2bfloat16(w);
    }

    const int j  = threadIdx.x & 127;
    const int rg = threadIdx.x >> 7;

    for (int base = blockIdx.x * 16; base < N; base += gridDim.x * 16) {
        const int rows = min(16, N - base);
        __syncthreads();
        for (int i = threadIdx.x; i < rows * 32; i += 256) {
            int r = i >> 5, c = i & 31;
            size_t gph = (size_t)(base + r) * (DFEAT / 4) + c;
            float4 hv = reinterpret_cast<const float4*>(out)[gph];
            float4 sv;
            if (BLEND) {
                float4 h0v = reinterpret_cast<const float4*>(h0)[gph];
                sv.x = oma * hv.x + a * h0v.x;
                sv.y = oma * hv.y + a * h0v.y;
                sv.z = oma * hv.z + a * h0v.z;
                sv.w = oma * hv.w + a * h0v.w;
            } else {
                sv = hv;
            }
            S4[r][c] = sv;
        }
        __syncthreads();

        float acc[8];
        #pragma unroll
        for (int r = 0; r < 8; r++) acc[r] = 0.0f;
        for (int k = 0; k < DFEAT; k += 4) {
            float w0 = __bfloat162float(Wl[(k + 0) * DFEAT + j]);
            float w1 = __bfloat162float(Wl[(k + 1) * DFEAT + j]);
            float w2 = __bfloat162float(Wl[(k + 2) * DFEAT + j]);
            float w3 = __bfloat162float(Wl[(k + 3) * DFEAT + j]);
            #pragma unroll
            for (int r = 0; r < 8; r++) {
                float4 s4 = S4[rg * 8 + r][k >> 2];
                acc[r] = fmaf(s4.x, w0, acc[r]);
                acc[r] = fmaf(s4.y, w1, acc[r]);
                acc[r] = fmaf(s4.z, w2, acc[r]);
                acc[r] = fmaf(s4.w, w3, acc[r]);
            }
        }
        #pragma unroll
        for (int r = 0; r < 8; r++) {
            int rr = rg * 8 + r;
            if (rr < rows) {
                size_t gph = (size_t)(base + rr) * DFEAT + j;
                out[gph] = acc[r] + inp[gph];
            }
        }
    }
}

extern "C" void kernel_launch(void* const* d_in, const int* in_sizes, int n_in,
                              void* d_out, int out_size, void* d_ws, size_t ws_size,
                              hipStream_t stream) {
    const float* input = (const float*)d_in[0];
    const int*   esrc  = (const int*)  d_in[1];
    const int*   edst  = (const int*)  d_in[2];
    const float* eval_ = (const float*)d_in[3];
    const float* h0    = (const float*)d_in[4];
    const float* W     = (const float*)d_in[5];
    const float* alpha = (const float*)d_in[6];

    const int N = in_sizes[0] / DFEAT;
    const int E = in_sizes[1];
    float* out = (float*)d_out;
    const int B = (N + 255) / 256;

    // ---- Plan A layout (bytes):
    //   in16[N*128*2] | csr[E*8] | rowptr[(N+1)*4] | cnt[N*4] | part[4096] | wprep[32K]
    size_t bA_in16   = 0;
    size_t bA_csr    = (bA_in16 + (size_t)N * DFEAT * 2 + 15) & ~(size_t)15;
    size_t bA_rowptr = bA_csr + (size_t)E * 8;
    size_t bA_cnt    = bA_rowptr + (size_t)(N + 1) * 4;
    size_t bA_part   = bA_cnt + (size_t)N * 4;
    size_t bA_wp     = (bA_part + 1024 * 4 + 15) & ~(size_t)15;
    size_t needA     = bA_wp + (size_t)DFEAT * DFEAT * 2;

    // ---- Plan B layout (ints): rowptr[N+1] | cnt[N] | part[1024] | csr[E]
    size_t o_rowptr = 0;
    size_t o_cnt    = o_rowptr + (size_t)(N + 1);
    size_t o_part   = o_cnt + (size_t)N;
    size_t o_csr    = (o_part + 1024 + 1) & ~(size_t)1;
    size_t needB    = o_csr * 4 + (size_t)E * 8;

    if (ws_size >= needA && B <= 1024) {
        unsigned short* in16 = (unsigned short*)((char*)d_ws + bA_in16);
        int2* csr    = (int2*)((char*)d_ws + bA_csr);
        int*  rowptr = (int*) ((char*)d_ws + bA_rowptr);
        int*  cnt    = (int*) ((char*)d_ws + bA_cnt);
        int*  part   = (int*) ((char*)d_ws + bA_part);
        unsigned short* wp = (unsigned short*)((char*)d_ws + bA_wp);

        int n8 = N * DFEAT / 8;
        int ntiles = (N + 15) / 16;
        int E4 = (E + 3) / 4;
        k_cvt  <<<dim3((n8 + 255) / 256), dim3(256), 0, stream>>>(input, (uint4*)in16, n8);
        k_wprep<<<dim3(8),               dim3(256), 0, stream>>>(W, wp);
        hipMemsetAsync(cnt, 0, (size_t)N * sizeof(int), stream);
        k_hist <<<dim3((E4 + 255) / 256), dim3(256), 0, stream>>>(edst, cnt, E);
        k_scanA<<<dim3(B),               dim3(256), 0, stream>>>(cnt, part, N);
        k_scanB<<<dim3(1),               dim3(1024), 0, stream>>>(part, rowptr, B, N);
        k_scanC<<<dim3(B),               dim3(256), 0, stream>>>(cnt, part, rowptr, N);
        k_slot <<<dim3((E4 + 255) / 256), dim3(256), 0, stream>>>(esrc, edst, eval_,
                                                                  rowptr, cnt, csr, E);
        k_fused2<<<dim3(2048),           dim3(256), 0, stream>>>(in16, csr, rowptr,
                                                                 h0, input, wp, alpha,
                                                                 out, N, ntiles);
    } else if (ws_size >= needB && B <= 1024) {
        int*  rowptr = (int*)d_ws + o_rowptr;
        int*  cnt    = (int*)d_ws + o_cnt;
        int*  part   = (int*)d_ws + o_part;
        int2* csr    = (int2*)((int*)d_ws + o_csr);
        int E4 = (E + 3) / 4;

        hipMemsetAsync(cnt, 0, (size_t)N * sizeof(int), stream);
        k_hist <<<dim3((E4 + 255) / 256), dim3(256), 0, stream>>>(edst, cnt, E);
        k_scanA<<<dim3(B),               dim3(256), 0, stream>>>(cnt, part, N);
        k_scanB<<<dim3(1),               dim3(1024), 0, stream>>>(part, rowptr, B, N);
        k_scanC<<<dim3(B),               dim3(256), 0, stream>>>(cnt, part, rowptr, N);
        k_slot <<<dim3((E4 + 255) / 256), dim3(256), 0, stream>>>(esrc, edst, eval_,
                                                                  rowptr, cnt, csr, E);
        k_gather<<<dim3((N + 3) / 4),    dim3(256), 0, stream>>>(input, csr, rowptr,
                                                                 h0, alpha, out, N);
        gcn_epilogue<false><<<dim3(2048), dim3(256), 0, stream>>>(out, h0, input, W,
                                                                  alpha, N);
    } else {
        hipMemsetAsync(out, 0, (size_t)N * DFEAT * sizeof(float), stream);
        long long threads = (long long)E * 64;
        unsigned  nblk    = (unsigned)((threads + 255) / 256);
        gcn_scatter<<<dim3(nblk), dim3(256), 0, stream>>>(input, esrc, edst, eval_, out, E);
        gcn_epilogue<true><<<dim3(2048), dim3(256), 0, stream>>>(out, h0, input, W,
                                                                 alpha, N);
    }
}